// Round 1
// 121.269 us; speedup vs baseline: 1.3865x; 1.3865x over previous
//
#include <hip/hip_runtime.h>
#include <math.h>

// ---------------- static problem structure (LMAX=4, taus=16) ----------------
#define NTRI 42
#define NCH  10752
#define B_SZ 256

typedef float    f32x4 __attribute__((ext_vector_type(4)));
typedef _Float16 half8 __attribute__((ext_vector_type(8)));
typedef _Float16 f16x2 __attribute__((ext_vector_type(2)));

// triples sorted by (l,l1,l2); CT_T = tile index within degree l
constexpr int CT_L [NTRI]={0,0,0,0,0, 1,1,1,1,1,1,1,1, 2,2,2,2,2,2,2,2,2,2, 3,3,3,3,3,3,3,3,3,3, 4,4,4,4,4,4,4,4,4};
constexpr int CT_L1[NTRI]={0,1,2,3,4, 1,1,2,2,3,3,4,4, 1,2,2,2,3,3,3,4,4,4, 2,2,3,3,3,3,4,4,4,4, 2,3,3,3,4,4,4,4,4};
constexpr int CT_L2[NTRI]={0,1,2,3,4, 0,1,1,2,2,3,3,4, 1,0,1,2,1,2,3,2,3,4, 1,2,0,1,2,3,1,2,3,4, 2,1,2,3,0,1,2,3,4};
constexpr int CT_T [NTRI]={0,1,2,3,4, 0,1,2,3,4,5,6,7, 0,1,2,3,4,5,6,7,8,9, 0,1,2,3,4,5,6,7,8,9, 0,1,2,3,4,5,6,7,8};

constexpr int KL_t[5]    ={1280,2048,2560,2560,2304};   // t_FF[l] (= K per degree)
constexpr int GBASE_t[5] ={0,1280,3328,5888,8448};      // channel base in varsum
constexpr int ROFF_t[5]  ={0,16,64,144,256};            // row offset in 400-row layout
constexpr int NM_t[5]    ={1,3,5,7,9};
// g_ff layout (f16x2 units): [l][m][b=256][c=K]; per-l base:
constexpr int FFB_t[5]   ={0,327680,1900544,5177344,9764864};
#define FF_TOT 15073280                                  // 60.3 MB of f16x2
// partial planes: one 16x16 (o x b) fp32 tile per (triple,m,bgroup); plane = 16bg*16o*16b
constexpr int PL_t[5]    ={0,5,29,79,149};               // plane base per degree
#define PART_PL 4096
#define PART_TOT (230*PART_PL)

// runtime tables (blockIdx-indexed)
__device__ const int   dCTL[NTRI]={0,0,0,0,0, 1,1,1,1,1,1,1,1, 2,2,2,2,2,2,2,2,2,2, 3,3,3,3,3,3,3,3,3,3, 4,4,4,4,4,4,4,4,4};
__device__ const int   dCTT[NTRI]={0,1,2,3,4, 0,1,2,3,4,5,6,7, 0,1,2,3,4,5,6,7,8,9, 0,1,2,3,4,5,6,7,8,9, 0,1,2,3,4,5,6,7,8};
__device__ const int   dK[5]   ={1280,2048,2560,2560,2304};
__device__ const int   dWOFF[5]={0,20480,53248,94208,135168};
__device__ const int   dNM[5]  ={1,3,5,7,9};
__device__ const int   dFFB[5] ={0,327680,1900544,5177344,9764864};
__device__ const int   dPL[5]  ={0,5,29,79,149};
__device__ const int   dGB[5]  ={0,1280,3328,5888,8448};
__device__ const int   dROFF[5]={0,16,64,144,256};
__device__ const int   dNT[5]  ={5,8,10,10,9};
__device__ const float dINV[5] ={1.f/256.f,1.f/768.f,1.f/1280.f,1.f/1792.f,1.f/2304.f}; // 1/(256*NM)

// ---------------- device globals ----------------
__device__ float  g_varsum[NCH];
__device__ __align__(16) f16x2  g_ff[FF_TOT];    // unnormalized FF, f16 (re,im)
__device__ float2 g_part[PART_TOT];              // per-tile GEMM partials

// ---------------- compile-time Clebsch-Gordan table ----------------
constexpr double cfact(int n){ double r=1.0; for(int i=2;i<=n;i++) r*=(double)i; return r; }
constexpr double csqrt_(double v){ double x = v>1.0? v:1.0; for(int i=0;i<80;i++) x = 0.5*(x+v/x); return x; }
constexpr double ccg(int j1,int m1,int j2,int m2,int j,int m){
    if(m1+m2!=m) return 0.0;
    double pref = csqrt_((2.0*j+1.0)*cfact(j+j1-j2)*cfact(j-j1+j2)*cfact(j1+j2-j)/cfact(j1+j2+j+1));
    pref *= csqrt_(cfact(j+m)*cfact(j-m)*cfact(j1-m1)*cfact(j1+m1)*cfact(j2-m2)*cfact(j2+m2));
    double s=0.0;
    for(int k=0;k<=j1+j2-j;k++){
        int a=j1-m1-k, bb=j2+m2-k, c=j-j2+m1+k, d=j-j1-m2+k;
        if(a<0||bb<0||c<0||d<0) continue;
        double term = 1.0/(cfact(k)*cfact(j1+j2-j-k)*cfact(a)*cfact(bb)*cfact(c)*cfact(d));
        s += (k&1)? -term : term;
    }
    return pref*s;
}
struct CG81 { float a[81]; };
constexpr CG81 makecg(int l,int l1,int l2){
    CG81 t{};
    const int n1=2*l1+1;
    for(int mi=0;mi<2*l+1;mi++)
        for(int p=0;p<n1;p++){
            const int m=mi-l, m1=p-l1, m2=m-m1;
            if(m2>=-l2 && m2<=l2) t.a[mi*n1+p]=(float)ccg(l1,m1,l2,m2,l,m);
        }
    return t;
}
// one static constexpr per triple: keeps each constant-expression small, and
// CG coefficients fold to immediates inside the fully-unrolled loops.
template<int TR> struct CGC { static constexpr CG81 t = makecg(CT_L[TR],CT_L1[TR],CT_L2[TR]); };

// ---------------- CG product in registers: thread = pair (i,j) ----------------
template<int TR>
__device__ __forceinline__ void cg_compute(const float2* __restrict__ FsB,
                                           int i, int j, float2* __restrict__ ff){
    constexpr int L=CT_L[TR], L1=CT_L1[TR], L2=CT_L2[TR];
    constexpr int N1=2*L1+1, N2=2*L2+1, NM=2*L+1;
    float2 A[N1], Bv[N2];
    #pragma unroll
    for(int p=0;p<N1;p++) A[p]=FsB[ROFF_t[L1]+i*N1+p];
    #pragma unroll
    for(int q=0;q<N2;q++) Bv[q]=FsB[ROFF_t[L2]+j*N2+q];
    #pragma unroll
    for(int mi=0;mi<NM;mi++){
        float aR=0.f, aI=0.f;
        const int pLo = (mi-L+L1-L2) > 0 ? (mi-L+L1-L2) : 0;
        const int pHi = (mi-L+L1+L2) < 2*L1 ? (mi-L+L1+L2) : 2*L1;
        #pragma unroll
        for(int p=0;p<N1;p++){
            if(p>=pLo && p<=pHi){               // folds at compile time
                const float c = CGC<TR>::t.a[mi*N1+p];   // folds to literal after unroll
                if(c != 0.f){
                    const int q = mi - L - p + L1 + L2;
                    const float2 a=A[p], b=Bv[q];
                    aR = fmaf(c, a.x*b.x - a.y*b.y, aR);
                    aI = fmaf(c, a.x*b.y + a.y*b.x, aI);
                }
            }
        }
        ff[mi]=make_float2(aR,aI);
    }
}

// ------- kernel 1: CG once -> f16 FF to global + variance atomics -------------
template<int TR>
__device__ __forceinline__ void cg_one(const float2* __restrict__ Fs, int bc, int t){
    constexpr int L=CT_L[TR], NM=2*L+1, T=CT_T[TR], K=KL_t[L];
    constexpr int MPL=256*K;                    // f16x2 per m-plane
    const int i=t>>4, j=t&15;
    float n2=0.f;
    for(int b4=0;b4<4;b4++){
        const int b=bc*4+b4;
        float2 ff[NM];
        cg_compute<TR>(Fs + b*400, i, j, ff);
        const int base = FFB_t[L] + b*K + T*256 + t;
        #pragma unroll
        for(int m=0;m<NM;m++){
            n2 = fmaf(ff[m].x,ff[m].x,n2);
            n2 = fmaf(ff[m].y,ff[m].y,n2);
            f16x2 h; h.x=(_Float16)ff[m].x; h.y=(_Float16)ff[m].y;
            g_ff[base + m*MPL] = h;             // lanes -> consecutive 4B: coalesced
        }
    }
    atomicAdd(&g_varsum[GBASE_t[L] + CT_T[TR]*256 + t], n2);
}

template<int TR>
__device__ __forceinline__ void cg_disp(int tr, const float2* Fs, int bc, int t){
    if constexpr (TR < NTRI){
        if(tr==TR) cg_one<TR>(Fs,bc,t);
        else       cg_disp<TR+1>(tr,Fs,bc,t);
    }
}

__global__ void __launch_bounds__(256) k_cg(const float2* __restrict__ Fs){
    cg_disp<0>(blockIdx.x, Fs, blockIdx.y, threadIdx.x);
}

// ------- kernel 2: MFMA GEMM. 1 wave per (triple, bgroup, m) ------------------
// Complex matmul via K-stacked real MFMA (k' = 2c+ri):
//   Yr rows: A=[Wr,-Wi]*invv ; Yi rows: A=[Wi, Wr]*invv ; shared B=[Xr;Xi] (f16)
// Frags (16x16x32): A row = lane&15 (=o), B col = lane&15 (=b_local),
//   per-lane k = (lane>>4)*8 + e (identical map for A and B -> any k-permute cancels),
//   D: col=lane&15, row=(lane>>4)*4+r  [HW-verified layout].
__global__ void __launch_bounds__(64) k_mm(const float2* __restrict__ W2){
    const int tr=blockIdx.x, bg=blockIdx.y, m=blockIdx.z;
    const int l=dCTL[tr];
    const int NM=dNM[l];
    if(m>=NM) return;
    const int T=dCTT[tr], K=dK[l];
    const int lane=threadIdx.x;
    const int l15=lane&15, kg=lane>>4;
    // c-base this lane covers per k-step: T*256 + ks*16 + kg*4 .. +3
    const float4* __restrict__ Wv = reinterpret_cast<const float4*>(W2 + dWOFF[l] + l15*K) + T*128 + kg*2;
    const float4* __restrict__ Vv = reinterpret_cast<const float4*>(g_varsum + dGB[l] + T*256) + kg;
    const f16x2*  __restrict__ Xp = g_ff + dFFB[l] + m*(256*K) + (bg*16 + l15)*K + T*256 + kg*4;
    const float inv = dINV[l];
    f32x4 ar0={0.f,0.f,0.f,0.f}, ar1={0.f,0.f,0.f,0.f};
    f32x4 ai0={0.f,0.f,0.f,0.f}, ai1={0.f,0.f,0.f,0.f};
    #pragma unroll
    for(int ks=0; ks<16; ks++){
        const float4 wa = Wv[ks*8];            // (Wr,Wi) of c0, c0+1
        const float4 wb = Wv[ks*8+1];          // (Wr,Wi) of c0+2, c0+3
        const float4 vs = Vv[ks*4];            // varsum of c0..c0+3
        const float s0 = 1.f/(sqrtf(vs.x*inv)+1e-5f);
        const float s1 = 1.f/(sqrtf(vs.y*inv)+1e-5f);
        const float s2 = 1.f/(sqrtf(vs.z*inv)+1e-5f);
        const float s3 = 1.f/(sqrtf(vs.w*inv)+1e-5f);
        half8 Ar, Ai;
        Ar[0]=(_Float16)( wa.x*s0); Ar[1]=(_Float16)(-wa.y*s0);
        Ar[2]=(_Float16)( wa.z*s1); Ar[3]=(_Float16)(-wa.w*s1);
        Ar[4]=(_Float16)( wb.x*s2); Ar[5]=(_Float16)(-wb.y*s2);
        Ar[6]=(_Float16)( wb.z*s3); Ar[7]=(_Float16)(-wb.w*s3);
        Ai[0]=(_Float16)( wa.y*s0); Ai[1]=(_Float16)( wa.x*s0);
        Ai[2]=(_Float16)( wa.w*s1); Ai[3]=(_Float16)( wa.z*s1);
        Ai[4]=(_Float16)( wb.y*s2); Ai[5]=(_Float16)( wb.x*s2);
        Ai[6]=(_Float16)( wb.w*s3); Ai[7]=(_Float16)( wb.z*s3);
        const half8 Bf = *reinterpret_cast<const half8*>(Xp + ks*16);  // 16B aligned
        if(ks & 1){
            ar1 = __builtin_amdgcn_mfma_f32_16x16x32_f16(Ar, Bf, ar1, 0,0,0);
            ai1 = __builtin_amdgcn_mfma_f32_16x16x32_f16(Ai, Bf, ai1, 0,0,0);
        } else {
            ar0 = __builtin_amdgcn_mfma_f32_16x16x32_f16(Ar, Bf, ar0, 0,0,0);
            ai0 = __builtin_amdgcn_mfma_f32_16x16x32_f16(Ai, Bf, ai0, 0,0,0);
        }
    }
    const f32x4 ar = ar0 + ar1, ai = ai0 + ai1;
    // D: row=o=(kg*4+r), col=b_local=l15 ; plane layout [bg][o][b]
    float2* __restrict__ pp = g_part + (dPL[l] + T*NM + m)*PART_PL + bg*256;
    #pragma unroll
    for(int r=0;r<4;r++){
        pp[(kg*4+r)*16 + l15] = make_float2(ar[r], ai[r]);
    }
}

// ------- kernel 3: reduce tile partials -> out --------------------------------
__global__ void __launch_bounds__(448) k_red(float2* __restrict__ out){
    const int b=blockIdx.x, r=threadIdx.x;
    if(r>=400) return;
    const int l = (r<16)?0:(r<64)?1:(r<144)?2:(r<256)?3:4;
    const int om = r - dROFF[l];               // = o*NM + m
    const int nm = dNM[l];
    const int o = om/nm, m = om - o*nm;
    const float2* __restrict__ pp = g_part + (dPL[l]+m)*PART_PL + (b>>4)*256 + o*16 + (b&15);
    float2 s=make_float2(0.f,0.f);
    const int nt=dNT[l];
    for(int T=0;T<nt;T++){
        const float2 v = pp[T*nm*PART_PL];
        s.x+=v.x; s.y+=v.y;
    }
    out[b*400+r]=s;
}

// ---------------- launcher ----------------
extern "C" void kernel_launch(void* const* d_in, const int* in_sizes, int n_in,
                              void* d_out, int out_size, void* d_ws, size_t ws_size,
                              hipStream_t stream){
    const float2* Fs = (const float2*)d_in[0];   // [256,400,2] fp32
    const float2* W  = (const float2*)d_in[1];   // [172032,2]  fp32
    float2* out = (float2*)d_out;                // [256,400,2] fp32

    void* dvs=nullptr;
    hipGetSymbolAddress(&dvs, HIP_SYMBOL(g_varsum));
    hipMemsetAsync(dvs, 0, NCH*sizeof(float), stream);

    k_cg <<<dim3(NTRI,64),   256, 0, stream>>>(Fs);
    k_mm <<<dim3(NTRI,16,9),  64, 0, stream>>>(W);
    k_red<<<dim3(B_SZ),      448, 0, stream>>>(out);
}